// Round 4
// baseline (416.456 us; speedup 1.0000x reference)
//
#include <hip/hip_runtime.h>

#define EPS_F 1e-6f

typedef float f32x4 __attribute__((ext_vector_type(4)));

__global__ __launch_bounds__(256) void mueller_kernel(
    const float* __restrict__ cos_theta_i,
    const float* __restrict__ eta_arr,
    f32x4* __restrict__ out, int n)
{
    int i = blockIdx.x * blockDim.x + threadIdx.x;
    if (i >= n) return;

    float ci   = cos_theta_i[i];
    float eta  = eta_arr[i];
    float rcp_eta = 1.0f / eta;
    bool  outside = (ci >= 0.0f);
    float eta_it = outside ? eta : rcp_eta;
    float eta_ti = outside ? rcp_eta : eta;

    float cts    = 1.0f - eta_ti * eta_ti * (1.0f - ci * ci);
    float ci_abs = fabsf(ci);

    // sqrtz: complex sqrt of (cts + EPS + 0j), then mulsign by sign(cts)
    float x   = cts + EPS_F;
    float sgn = (cts >= 0.0f) ? 1.0f : -1.0f;
    float ctt_re, ctt_im;
    if (x >= 0.0f) { ctt_re = sqrtf(x) * sgn;  ctt_im = 0.0f; }
    else           { ctt_re = 0.0f;            ctt_im = sqrtf(-x) * sgn; }

    // a_s = (A - eta_it*ctt) / (A + eta_it*ctt), A = |ci|  (complex)
    float A    = ci_abs;
    float u_re = eta_it * ctt_re;
    float u_im = eta_it * ctt_im;
    float ds2  = (A + u_re) * (A + u_re) + u_im * u_im;
    float inv_ds = 1.0f / ds2;
    float as_re = (A * A - u_re * u_re - u_im * u_im) * inv_ds;
    float as_im = (-2.0f * A * u_im) * inv_ds;

    // a_p = (B - ctt) / (B + ctt), B = eta_it*|ci|  (complex)
    float B    = eta_it * ci_abs;
    float dp2  = (B + ctt_re) * (B + ctt_re) + ctt_im * ctt_im;
    float inv_dp = 1.0f / dp2;
    float ap_re = (B * B - ctt_re * ctt_re - ctt_im * ctt_im) * inv_dp;
    float ap_im = (-2.0f * B * ctt_im) * inv_dp;

    if (eta == 1.0f || eta == 0.0f) {     // dead for these inputs; fidelity
        as_re = as_im = ap_re = ap_im = 0.0f;
    }

    float r_s  = as_re * as_re + as_im * as_im;
    float r_p  = ap_re * ap_re + ap_im * ap_im;
    float prod = r_p * r_s;

    float s    = sqrtf(prod + EPS_F);     // c (>= 1e-3 here; c==0 guard dead)
    float norm = (prod == 0.0f) ? 0.0f : 1.0f / s;
    float cos_d = (ap_re * as_re + ap_im * as_im) * norm;
    float sin_d = (ap_im * as_re - ap_re * as_im) * norm;

    float a = 0.5f * (r_s + r_p);
    float b = 0.5f * (r_s - r_p);
    float cc = s * cos_d;
    float cs = s * sin_d;

    f32x4* o = out + (size_t)i * 4;
    f32x4 r0 = {a,    b,    0.0f, 0.0f};
    f32x4 r1 = {b,    a,    0.0f, 0.0f};
    f32x4 r2 = {0.0f, 0.0f, cc,   -cs };
    f32x4 r3 = {0.0f, 0.0f, cs,   cc  };
    __builtin_nontemporal_store(r0, o + 0);
    __builtin_nontemporal_store(r1, o + 1);
    __builtin_nontemporal_store(r2, o + 2);
    __builtin_nontemporal_store(r3, o + 3);
}

extern "C" void kernel_launch(void* const* d_in, const int* in_sizes, int n_in,
                              void* d_out, int out_size, void* d_ws, size_t ws_size,
                              hipStream_t stream) {
    const float* ci  = (const float*)d_in[0];
    const float* eta = (const float*)d_in[1];
    f32x4* out = (f32x4*)d_out;
    int n = in_sizes[0];
    int block = 256;
    int grid = (n + block - 1) / block;
    mueller_kernel<<<grid, block, 0, stream>>>(ci, eta, out, n);
}

// Round 5
// 253.389 us; speedup vs baseline: 1.6435x; 1.6435x over previous
//
#include <hip/hip_runtime.h>

#define EPS_F 1e-6f

typedef float f32x4 __attribute__((ext_vector_type(4)));

__device__ __forceinline__ void mueller_vals(float ci, float eta,
                                             float& a, float& b,
                                             float& cc, float& cs)
{
    float rcp_eta = 1.0f / eta;
    bool  outside = (ci >= 0.0f);
    float eta_it = outside ? eta : rcp_eta;
    float eta_ti = outside ? rcp_eta : eta;

    float cts    = 1.0f - eta_ti * eta_ti * (1.0f - ci * ci);
    float ci_abs = fabsf(ci);

    // sqrtz: complex sqrt of (cts + EPS + 0j), then mulsign by sign(cts)
    float x   = cts + EPS_F;
    float sgn = (cts >= 0.0f) ? 1.0f : -1.0f;
    float ctt_re, ctt_im;
    if (x >= 0.0f) { ctt_re = sqrtf(x) * sgn;  ctt_im = 0.0f; }
    else           { ctt_re = 0.0f;            ctt_im = sqrtf(-x) * sgn; }

    // a_s = (A - eta_it*ctt) / (A + eta_it*ctt), A = |ci|  (complex)
    float A    = ci_abs;
    float u_re = eta_it * ctt_re;
    float u_im = eta_it * ctt_im;
    float ds2  = (A + u_re) * (A + u_re) + u_im * u_im;
    float inv_ds = 1.0f / ds2;
    float as_re = (A * A - u_re * u_re - u_im * u_im) * inv_ds;
    float as_im = (-2.0f * A * u_im) * inv_ds;

    // a_p = (B - ctt) / (B + ctt), B = eta_it*|ci|  (complex)
    float B    = eta_it * ci_abs;
    float dp2  = (B + ctt_re) * (B + ctt_re) + ctt_im * ctt_im;
    float inv_dp = 1.0f / dp2;
    float ap_re = (B * B - ctt_re * ctt_re - ctt_im * ctt_im) * inv_dp;
    float ap_im = (-2.0f * B * ctt_im) * inv_dp;

    if (eta == 1.0f || eta == 0.0f) {     // dead for these inputs; fidelity
        as_re = as_im = ap_re = ap_im = 0.0f;
    }

    float r_s  = as_re * as_re + as_im * as_im;
    float r_p  = ap_re * ap_re + ap_im * ap_im;
    float prod = r_p * r_s;

    float s    = sqrtf(prod + EPS_F);     // c (>= 1e-3 here; c==0 guard dead)
    float norm = (prod == 0.0f) ? 0.0f : 1.0f / s;
    float cos_d = (ap_re * as_re + ap_im * as_im) * norm;
    float sin_d = (ap_im * as_re - ap_re * as_im) * norm;

    a  = 0.5f * (r_s + r_p);
    b  = 0.5f * (r_s - r_p);
    cc = s * cos_d;
    cs = s * sin_d;
}

// 4 rays per thread: dwordx4 input loads, 16 back-to-back dwordx4 stores
// over a per-lane contiguous 256B slab (deep store MLP, L2 write-combined).
__global__ __launch_bounds__(256) void mueller_kernel(
    const float* __restrict__ ci_p,
    const float* __restrict__ eta_p,
    f32x4* __restrict__ out, int n)
{
    int t  = blockIdx.x * blockDim.x + threadIdx.x;
    int n4 = n >> 2;

    if (t < n4) {
        f32x4 civ  = reinterpret_cast<const f32x4*>(ci_p)[t];
        f32x4 etav = reinterpret_cast<const f32x4*>(eta_p)[t];

        f32x4 rows[16];
        #pragma unroll
        for (int j = 0; j < 4; ++j) {
            float a, b, cc, cs;
            mueller_vals(civ[j], etav[j], a, b, cc, cs);
            rows[4*j + 0] = (f32x4){a,    b,    0.0f, 0.0f};
            rows[4*j + 1] = (f32x4){b,    a,    0.0f, 0.0f};
            rows[4*j + 2] = (f32x4){0.0f, 0.0f, cc,   -cs };
            rows[4*j + 3] = (f32x4){0.0f, 0.0f, cs,   cc  };
        }

        f32x4* o = out + (size_t)t * 16;
        #pragma unroll
        for (int k = 0; k < 16; ++k) o[k] = rows[k];
    } else if (t == n4) {
        // tail rays (n % 4), scalar path
        for (int r = n4 * 4; r < n; ++r) {
            float a, b, cc, cs;
            mueller_vals(ci_p[r], eta_p[r], a, b, cc, cs);
            f32x4* o = out + (size_t)r * 4;
            o[0] = (f32x4){a,    b,    0.0f, 0.0f};
            o[1] = (f32x4){b,    a,    0.0f, 0.0f};
            o[2] = (f32x4){0.0f, 0.0f, cc,   -cs };
            o[3] = (f32x4){0.0f, 0.0f, cs,   cc  };
        }
    }
}

extern "C" void kernel_launch(void* const* d_in, const int* in_sizes, int n_in,
                              void* d_out, int out_size, void* d_ws, size_t ws_size,
                              hipStream_t stream) {
    const float* ci  = (const float*)d_in[0];
    const float* eta = (const float*)d_in[1];
    f32x4* out = (f32x4*)d_out;
    int n = in_sizes[0];
    int n4 = n >> 2;
    int rem = n & 3;
    long long threads = (long long)n4 + (rem ? 1 : 0);
    int block = 256;
    long long grid = (threads + block - 1) / block;
    mueller_kernel<<<(int)grid, block, 0, stream>>>(ci, eta, out, n);
}